// Round 12
// baseline (98.174 us; speedup 1.0000x reference)
//
#include <hip/hip_runtime.h>
#include <hip/hip_bf16.h>

#define LL 512
#define BB 32
#define DD 512
#define CINN 32
#define TOPK 6
#define BL (BB * LL)  // 16384

typedef __attribute__((ext_vector_type(8))) short bf16x8;
typedef __attribute__((ext_vector_type(4))) float f32x4;

__device__ inline float bf2f(ushort u) {
    union { uint i; float f; } c; c.i = ((uint)u) << 16; return c.f;
}
__device__ inline ushort f2bf(float f) {  // round-to-nearest-even
    union { float f; uint i; } c; c.f = f;
    uint i = c.i;
    return (ushort)((i + 0x7FFFu + ((i >> 16) & 1u)) >> 16);
}
__device__ inline void split_bf(float v, ushort& hi, ushort& lo) {
    hi = f2bf(v);
    lo = f2bf(v - bf2f(hi));
}
__device__ inline uint pk2(ushort a, ushort b) { return (uint)a | ((uint)b << 16); }

__device__ inline bf16x8 frag_ld(const ushort* sm, int r, int s) {
    return *(const bf16x8*)(sm + r * 32 + ((s ^ ((r >> 1) & 3)) << 3));
}

// One K=32 step of split-bf16 3-term MFMA (lo*lo dropped, ~2^-18).
__device__ inline void mfma_step(const ushort* sAh, const ushort* sAl,
                                 const ushort* sBh, const ushort* sBl,
                                 f32x4 acc[4][4], int wr, int wc, int fr, int fs) {
    bf16x8 bh[4], blo[4];
    #pragma unroll
    for (int ni = 0; ni < 4; ++ni) {
        bh[ni]  = frag_ld(sBh, wc + ni * 16 + fr, fs);
        blo[ni] = frag_ld(sBl, wc + ni * 16 + fr, fs);
    }
    #pragma unroll
    for (int mi = 0; mi < 4; ++mi) {
        const bf16x8 ah = frag_ld(sAh, wr + mi * 16 + fr, fs);
        const bf16x8 al = frag_ld(sAl, wr + mi * 16 + fr, fs);
        #pragma unroll
        for (int ni = 0; ni < 4; ++ni) {
            acc[mi][ni] = __builtin_amdgcn_mfma_f32_16x16x32_bf16(ah, bh[ni],  acc[mi][ni], 0, 0, 0);
            acc[mi][ni] = __builtin_amdgcn_mfma_f32_16x16x32_bf16(ah, blo[ni], acc[mi][ni], 0, 0, 0);
            acc[mi][ni] = __builtin_amdgcn_mfma_f32_16x16x32_bf16(al, bh[ni],  acc[mi][ni], 0, 0, 0);
        }
    }
}

// ---- K1: blocks 0..63:  e-chunk i (8 rows of wq,wk):
//            Aqc = wq_chunk@cw, Akc = wk_chunk@cw  ->  Mpart[i] = Aqc^T Akc.
//          blocks 64..71: upart[j][d] = sum_{n in 64-chunk} lin_w[n] wo[n][d].
//          block 64 (tid<32) also zeroes the per-batch completion counters.
__global__ __launch_bounds__(256) void prep_m(
    const float* __restrict__ wq, const float* __restrict__ wk,
    const float* __restrict__ cw,
    const float* __restrict__ lin_w, const float* __restrict__ wo,
    float* __restrict__ Mpart, float* __restrict__ upart,
    int* __restrict__ cnt)
{
    const int tid = threadIdx.x;
    if (blockIdx.x < 64) {
        __shared__ float cws[512][32];     // read: same d, c=bank -> conflict-free
        __shared__ float wqsT[512][9];     // stride 9: staging & reads conflict-free
        __shared__ float wksT[512][9];
        __shared__ float aqs[8][32];
        __shared__ float aks[8][32];
        for (int i = tid; i < 4096; i += 256) {
            const int d = i >> 3, q = i & 7;
            *(float4*)&cws[d][q * 4] = *(const float4*)(cw + (long)d * 32 + q * 4);
        }
        const int e0 = blockIdx.x * 8;
        for (int i = tid; i < 4096; i += 256) {
            const int e = i >> 9, d = i & 511;
            wqsT[d][e] = wq[(long)(e0 + e) * 512 + d];
            wksT[d][e] = wk[(long)(e0 + e) * 512 + d];
        }
        __syncthreads();
        const int e_loc = tid >> 5, c = tid & 31;
        float aq = 0.f, ak = 0.f;
        #pragma unroll 4
        for (int d = 0; d < 512; ++d) {
            const float cv = cws[d][c];
            aq += wqsT[d][e_loc] * cv;
            ak += wksT[d][e_loc] * cv;
        }
        aqs[e_loc][c] = aq;
        aks[e_loc][c] = ak;
        __syncthreads();
        const int c_ = tid >> 3, cq = tid & 7;
        float m0 = 0.f, m1 = 0.f, m2 = 0.f, m3 = 0.f;
        #pragma unroll
        for (int e = 0; e < 8; ++e) {
            const float a = aqs[e][c_];
            const float4 k4 = *(const float4*)&aks[e][cq * 4];
            m0 += a * k4.x; m1 += a * k4.y; m2 += a * k4.z; m3 += a * k4.w;
        }
        *(float4*)(Mpart + (long)blockIdx.x * 1024 + c_ * 32 + cq * 4) =
            make_float4(m0, m1, m2, m3);
    } else {
        const int j = blockIdx.x - 64;
        if (blockIdx.x == 64 && tid < BB) cnt[tid] = 0;   // zero completion counters
        const int n0 = j * 64;
        float u0 = 0.f, u1 = 0.f;
        for (int n = 0; n < 64; ++n) {
            const float lw = lin_w[n0 + n];
            u0 += lw * wo[(long)(n0 + n) * 512 + tid];
            u1 += lw * wo[(long)(n0 + n) * 512 + tid + 256];
        }
        upart[j * 512 + tid] = u0;
        upart[j * 512 + tid + 256] = u1;
    }
}

// ---- K2 (512 blocks): per (batch, 128x128 tile): in-block M-reduce
//      (ascending p, deterministic), build X/U tiles in LDS, one K=32
//      3-term MFMA, wrapped-diag reduce -> mcpart tile. The LAST block of
//      each batch (device atomic counter + fences) then runs the whole
//      per-batch tail: mc-reduce + top-6 + softmax + local v2/w3/w4/c2 + y.
__global__ __launch_bounds__(256, 2) void corr_tail(
    const float* __restrict__ x, const float* __restrict__ Mpart,
    const float* __restrict__ upart, const float* __restrict__ wv,
    const float* __restrict__ cw, const float* __restrict__ cb,
    const float* __restrict__ lin_w, const float* __restrict__ bv,
    const float* __restrict__ bo, const float* __restrict__ lin_b,
    float* __restrict__ mcpart, int* __restrict__ cnt,
    float* __restrict__ out)
{
    __shared__ ushort buf[16384];   // 4 regions x (128 rows x 4 units x 8 ush)
    __shared__ float Ml[32][36];
    __shared__ float mcloc[LL];
    __shared__ int lastflag;
    ushort* bufAh = buf;
    ushort* bufAl = buf + 4096;
    ushort* bufBh = buf + 8192;
    ushort* bufBl = buf + 12288;
    const int tid = threadIdx.x;

    const int xcd = blockIdx.x & 7, s = blockIdx.x >> 3;
    const int b = xcd * 4 + (s >> 4);
    const int tile = s & 15;
    const int tm = tile >> 2, tn = tile & 3;

    // M reduce (ascending p -> bit-identical across blocks/rounds)
    {
        float4 ms = make_float4(0.f, 0.f, 0.f, 0.f);
        for (int p = 0; p < 64; ++p) {
            const float4 v = *(const float4*)(Mpart + (long)p * 1024 + tid * 4);
            ms.x += v.x; ms.y += v.y; ms.z += v.z; ms.w += v.w;
        }
        *(float4*)&Ml[tid >> 3][(tid & 7) * 4] = ms;
    }
    mcloc[tid] = 0.f; mcloc[tid + 256] = 0.f;

    // per-thread build: 2 physical 16B units of one row per region
    const int r = tid >> 1;               // 0..127
    const int pb = (tid & 1) * 2;         // phys slots {0,1} or {2,3}
    const int swz = (r >> 1) & 3;
    const float* xA = x + ((long)b * LL + tm * 128 + r) * 32;
    const float* xB = x + ((long)b * LL + tn * 128 + r) * 32;
    float xb[32];
    #pragma unroll
    for (int q = 0; q < 8; ++q)
        *(float4*)&xb[q * 4] = *(const float4*)(xB + q * 4);

    __syncthreads();   // Ml + mcloc ready

    #pragma unroll
    for (int pi = 0; pi < 2; ++pi) {
        const int p = pb + pi;
        const int sl = p ^ swz;           // logical 8-col slot
        const int uoff = (r * 4 + p) * 8; // linear ushort offset in region
        const float4 a0 = *(const float4*)(xA + sl * 8);
        const float4 a1 = *(const float4*)(xA + sl * 8 + 4);
        const float xe[8] = {a0.x, a0.y, a0.z, a0.w, a1.x, a1.y, a1.z, a1.w};
        ushort xh[8], xl[8];
        #pragma unroll
        for (int j = 0; j < 8; ++j) split_bf(xe[j], xh[j], xl[j]);
        *(uint4*)(bufAh + uoff) = make_uint4(pk2(xh[0], xh[1]), pk2(xh[2], xh[3]),
                                             pk2(xh[4], xh[5]), pk2(xh[6], xh[7]));
        *(uint4*)(bufAl + uoff) = make_uint4(pk2(xl[0], xl[1]), pk2(xl[2], xl[3]),
                                             pk2(xl[4], xl[5]), pk2(xl[6], xl[7]));
        // U slot: u[c] = sum_d M[c][d] x[d] (q-ascending, bit-stable order)
        float uv[8];
        #pragma unroll
        for (int j = 0; j < 8; ++j) {
            const int c = sl * 8 + j;
            float sacc = 0.f;
            #pragma unroll
            for (int q = 0; q < 8; ++q) {
                const float4 m = *(const float4*)&Ml[c][q * 4];
                sacc += m.x * xb[q * 4] + m.y * xb[q * 4 + 1]
                      + m.z * xb[q * 4 + 2] + m.w * xb[q * 4 + 3];
            }
            uv[j] = sacc;
        }
        ushort uh[8], ul[8];
        #pragma unroll
        for (int j = 0; j < 8; ++j) split_bf(uv[j], uh[j], ul[j]);
        *(uint4*)(bufBh + uoff) = make_uint4(pk2(uh[0], uh[1]), pk2(uh[2], uh[3]),
                                             pk2(uh[4], uh[5]), pk2(uh[6], uh[7]));
        *(uint4*)(bufBl + uoff) = make_uint4(pk2(ul[0], ul[1]), pk2(ul[2], ul[3]),
                                             pk2(ul[4], ul[5]), pk2(ul[6], ul[7]));
    }
    __syncthreads();   // tiles built

    {
        const int wid = tid >> 6, lane = tid & 63;
        const int wr = (wid >> 1) * 64, wc = (wid & 1) * 64;
        const int fr = lane & 15, fs = lane >> 4;
        f32x4 acc[4][4] = {};
        mfma_step(bufAh, bufAl, bufBh, bufBl, acc, wr, wc, fr, fs);

        // pre-sum same-diagonal accs: diag = 16k + base, k = mi-ni
        const int base = wr - wc + 128 * (tm - tn) + fs * 4 - fr;
        #pragma unroll
        for (int k = -3; k <= 3; ++k) {
            #pragma unroll
            for (int rr = 0; rr < 4; ++rr) {
                float sdg = 0.f;
                #pragma unroll
                for (int mi = 0; mi < 4; ++mi) {
                    const int ni = mi - k;
                    if (ni >= 0 && ni < 4) sdg += acc[mi][ni][rr];
                }
                atomicAdd(&mcloc[(base + 16 * k + rr) & (LL - 1)], sdg);
            }
        }
    }
    __syncthreads();
    {
        float* o = mcpart + ((long)b * 16 + tile) * LL;
        o[tid] = mcloc[tid];
        o[tid + 256] = mcloc[tid + 256];
    }
    // publish this tile, then let the last block of the batch run the tail
    __threadfence();
    __syncthreads();
    if (tid == 0) lastflag = (atomicAdd(&cnt[b], 1) == 15) ? 1 : 0;
    __syncthreads();
    if (!lastflag) return;
    __threadfence();   // acquire: other blocks' mcpart writes now visible

    // ---------------- per-batch tail (one block per batch) ----------------
    {
        const int lane = tid & 63, wid = tid >> 6;
        float* fb   = (float*)buf;           // reuse 32KB LDS
        float* v2s  = fb;                    // 512
        float* us2  = fb + 512;              // 512
        float (*w3p)[32] = (float(*)[32])(fb + 1024);  // 8x32
        float (*w4p)[32] = (float(*)[32])(fb + 1280);  // 8x32
        float* w3s  = fb + 1536;             // 32
        float* w4s  = fb + 1568;             // 32
        float* swv  = fb + 1600;             // 4
        float* selv = fb + 1604;             // 6
        float* wts  = fb + 1610;             // 6
        float* redc = fb + 1616;             // 4
        float* c2s  = fb + 1620;             // 1
        int*   swi  = (int*)(fb + 1624);     // 4
        int*   seli = (int*)(fb + 1628);     // 6

        // u = sum upart (ascending i -> same bits as before)
        {
            float b0 = 0.f, b1 = 0.f;
            #pragma unroll
            for (int i = 0; i < 8; ++i) {
                b0 += upart[i * 512 + tid];
                b1 += upart[i * 512 + tid + 256];
            }
            us2[tid] = b0; us2[tid + 256] = b1;
        }
        __syncthreads();
        // v2[e] = sum_d u[d] wv[d][e]  (d ascending; y-path only)
        {
            float s0 = 0.f, s1 = 0.f;
            for (int d = 0; d < 512; ++d) {
                const float ud = us2[d];
                s0 += ud * wv[(long)d * 512 + tid];
                s1 += ud * wv[(long)d * 512 + tid + 256];
            }
            v2s[tid] = s0; v2s[tid + 256] = s1;
        }
        __syncthreads();
        {
            const int c = tid & 31, g = tid >> 5;
            float w3 = 0.f, w4 = 0.f;
            for (int dl = 0; dl < 64; ++dl) {
                const int d = g * 64 + dl;
                const float cwv = cw[(long)d * 32 + c];
                w3 += v2s[d] * cwv;
                w4 += lin_w[d] * cwv;
            }
            w3p[g][c] = w3; w4p[g][c] = w4;
        }
        __syncthreads();
        if (tid < 32) {
            float a3 = 0.f, a4 = 0.f;
            #pragma unroll
            for (int g2 = 0; g2 < 8; ++g2) { a3 += w3p[g2][tid]; a4 += w4p[g2][tid]; }
            w3s[tid] = a3; w4s[tid] = a4;
        }
        {
            float p = cb[tid] * (v2s[tid] + lin_w[tid])
                    + cb[tid + 256] * (v2s[tid + 256] + lin_w[tid + 256])
                    + bv[tid] * us2[tid] + bv[tid + 256] * us2[tid + 256]
                    + bo[tid] * lin_w[tid] + bo[tid + 256] * lin_w[tid + 256];
            #pragma unroll
            for (int o = 32; o; o >>= 1) p += __shfl_down(p, o);
            if ((tid & 63) == 0) redc[tid >> 6] = p;
        }
        __syncthreads();
        if (tid == 0) c2s[0] = redc[0] + redc[1] + redc[2] + redc[3] + lin_b[0];

        // mc reduce (ascending j -> bit-identical to the multi-kernel version)
        float v0 = 0.f, v1 = 0.f;
        #pragma unroll
        for (int j = 0; j < 16; ++j) {
            v0 += mcpart[((long)b * 16 + j) * LL + tid];
            v1 += mcpart[((long)b * 16 + j) * LL + tid + 256];
        }
        v0 *= (1.0f / DD); v1 *= (1.0f / DD);

        // top-6 via wave shuffle (max value, min index on ties)
        int live0 = 1, live1 = 1;
        for (int rr = 0; rr < TOPK; ++rr) {
            float bvv = -1e30f; int bi = -1;
            if (live0) { bvv = v0; bi = tid; }
            if (live1 && v1 > bvv) { bvv = v1; bi = tid + 256; }
            #pragma unroll
            for (int o = 32; o; o >>= 1) {
                const float ov = __shfl_down(bvv, o);
                const int oi = __shfl_down(bi, o);
                if (ov > bvv || (ov == bvv && oi < bi)) { bvv = ov; bi = oi; }
            }
            if (lane == 0) { swv[wid] = bvv; swi[wid] = bi; }
            __syncthreads();
            if (tid == 0) {
                float fv = swv[0]; int fi = swi[0];
                #pragma unroll
                for (int w2 = 1; w2 < 4; ++w2) {
                    if (swv[w2] > fv || (swv[w2] == fv && swi[w2] < fi)) { fv = swv[w2]; fi = swi[w2]; }
                }
                selv[rr] = fv; seli[rr] = fi;
            }
            __syncthreads();
            const int w = seli[rr];
            if (w == tid)       live0 = 0;
            if (w == tid + 256) live1 = 0;
        }
        if (tid == 0) {
            const float mx = selv[0];
            float e[TOPK], ssum = 0.f;
            #pragma unroll
            for (int k = 0; k < TOPK; ++k) { e[k] = expf(selv[k] - mx); ssum += e[k]; }
            #pragma unroll
            for (int k = 0; k < TOPK; ++k) wts[k] = e[k] / ssum;
        }
        __syncthreads();

        // y = <xlast, w4> + <xmix, w3> + c2
        if (tid < CINN) {
            float xm = 0.f;
            #pragma unroll
            for (int k = 0; k < TOPK; ++k) {
                const int rr = (LL - 1 + seli[k]) & (LL - 1);
                xm += wts[k] * x[((long)b * LL + rr) * CINN + tid];
            }
            const float xlv = x[((long)b * LL + (LL - 1)) * CINN + tid];
            float yv = xlv * w4s[tid] + xm * w3s[tid];
            #pragma unroll
            for (int o = 16; o; o >>= 1) yv += __shfl_down(yv, o);
            if (tid == 0) out[b] = yv + c2s[0];
        }
    }
}

extern "C" void kernel_launch(void* const* d_in, const int* in_sizes, int n_in,
                              void* d_out, int out_size, void* d_ws, size_t ws_size,
                              hipStream_t stream) {
    const float* x      = (const float*)d_in[0];
    const float* conv_w = (const float*)d_in[1];
    const float* conv_b = (const float*)d_in[2];
    const float* wq     = (const float*)d_in[3];
    const float* wk     = (const float*)d_in[5];
    const float* wv     = (const float*)d_in[7];
    const float* bv     = (const float*)d_in[8];
    const float* wo     = (const float*)d_in[9];
    const float* bo     = (const float*)d_in[10];
    const float* lin_w  = (const float*)d_in[11];
    const float* lin_b  = (const float*)d_in[12];
    // bq, bk and all bias terms inside mean_corr are tau-constant -> dropped
    // (softmax/top-k shift-invariant).

    char* w = (char*)d_ws;
    float* Mpart  = (float*)w;  w += (long)64 * 1024 * 4;      // 256 KB
    float* upart  = (float*)w;  w += (long)8 * 512 * 4;        // 16 KB
    float* mcpart = (float*)w;  w += (long)BB * 16 * LL * 4;   // 1 MB
    int*   cnt    = (int*)w;    w += BB * 4;
    float* yout   = (float*)d_out;

    // Mpart (0..63) | upart (64..71) + counter zeroing (block 64)
    prep_m<<<72, 256, 0, stream>>>(wq, wk, conv_w, lin_w, wo, Mpart, upart, cnt);
    // corr tiles + last-block-per-batch tail
    corr_tail<<<512, 256, 0, stream>>>(x, Mpart, upart, wv,
                                       conv_w, conv_b, lin_w, bv, bo, lin_b,
                                       mcpart, cnt, yout);
}

// Round 13
// 70.112 us; speedup vs baseline: 1.4003x; 1.4003x over previous
//
#include <hip/hip_runtime.h>
#include <hip/hip_bf16.h>

#define LL 512
#define BB 32
#define DD 512
#define CINN 32
#define TOPK 6
#define BL (BB * LL)  // 16384

typedef __attribute__((ext_vector_type(8))) short bf16x8;
typedef __attribute__((ext_vector_type(4))) float f32x4;

__device__ inline float bf2f(ushort u) {
    union { uint i; float f; } c; c.i = ((uint)u) << 16; return c.f;
}
__device__ inline ushort f2bf(float f) {  // round-to-nearest-even
    union { float f; uint i; } c; c.f = f;
    uint i = c.i;
    return (ushort)((i + 0x7FFFu + ((i >> 16) & 1u)) >> 16);
}
__device__ inline void split_bf(float v, ushort& hi, ushort& lo) {
    hi = f2bf(v);
    lo = f2bf(v - bf2f(hi));
}
__device__ inline uint pk2(ushort a, ushort b) { return (uint)a | ((uint)b << 16); }

__device__ inline bf16x8 frag_ld(const ushort* sm, int r, int s) {
    return *(const bf16x8*)(sm + r * 32 + ((s ^ ((r >> 1) & 3)) << 3));
}

// One K=32 step of split-bf16 3-term MFMA (lo*lo dropped, ~2^-18).
__device__ inline void mfma_step(const ushort* sAh, const ushort* sAl,
                                 const ushort* sBh, const ushort* sBl,
                                 f32x4 acc[4][4], int wr, int wc, int fr, int fs) {
    bf16x8 bh[4], blo[4];
    #pragma unroll
    for (int ni = 0; ni < 4; ++ni) {
        bh[ni]  = frag_ld(sBh, wc + ni * 16 + fr, fs);
        blo[ni] = frag_ld(sBl, wc + ni * 16 + fr, fs);
    }
    #pragma unroll
    for (int mi = 0; mi < 4; ++mi) {
        const bf16x8 ah = frag_ld(sAh, wr + mi * 16 + fr, fs);
        const bf16x8 al = frag_ld(sAl, wr + mi * 16 + fr, fs);
        #pragma unroll
        for (int ni = 0; ni < 4; ++ni) {
            acc[mi][ni] = __builtin_amdgcn_mfma_f32_16x16x32_bf16(ah, bh[ni],  acc[mi][ni], 0, 0, 0);
            acc[mi][ni] = __builtin_amdgcn_mfma_f32_16x16x32_bf16(ah, blo[ni], acc[mi][ni], 0, 0, 0);
            acc[mi][ni] = __builtin_amdgcn_mfma_f32_16x16x32_bf16(al, bh[ni],  acc[mi][ni], 0, 0, 0);
        }
    }
}

// ---- K1 (65 blocks):
//  blocks 0..63: e-chunk i (8 rows of wq,wk): Mpart[i] = (wq_c@cw)^T (wk_c@cw).
//                blocks 0..31 also zero mc[b] (re-zeroed every launch).
//  block 64:     u = wo^T lin_w (in-block), then v2 = wv^T u -> ug, v2g.
__global__ __launch_bounds__(256) void prep_kernel(
    const float* __restrict__ wq, const float* __restrict__ wk,
    const float* __restrict__ cw,
    const float* __restrict__ lin_w, const float* __restrict__ wo,
    const float* __restrict__ wv,
    float* __restrict__ Mpart, float* __restrict__ ug,
    float* __restrict__ v2g, float* __restrict__ mc)
{
    const int tid = threadIdx.x;
    if (blockIdx.x < 64) {
        __shared__ float cws[512][32];     // read: same d, c=bank -> conflict-free
        __shared__ float wqsT[512][9];     // stride 9: staging & reads conflict-free
        __shared__ float wksT[512][9];
        __shared__ float aqs[8][32];
        __shared__ float aks[8][32];
        if (blockIdx.x < 32) {             // zero mc for this batch
            mc[blockIdx.x * 512 + tid] = 0.f;
            mc[blockIdx.x * 512 + tid + 256] = 0.f;
        }
        for (int i = tid; i < 4096; i += 256) {
            const int d = i >> 3, q = i & 7;
            *(float4*)&cws[d][q * 4] = *(const float4*)(cw + (long)d * 32 + q * 4);
        }
        const int e0 = blockIdx.x * 8;
        for (int i = tid; i < 4096; i += 256) {
            const int e = i >> 9, d = i & 511;
            wqsT[d][e] = wq[(long)(e0 + e) * 512 + d];
            wksT[d][e] = wk[(long)(e0 + e) * 512 + d];
        }
        __syncthreads();
        const int e_loc = tid >> 5, c = tid & 31;
        float aq = 0.f, ak = 0.f;
        #pragma unroll 4
        for (int d = 0; d < 512; ++d) {
            const float cv = cws[d][c];
            aq += wqsT[d][e_loc] * cv;
            ak += wksT[d][e_loc] * cv;
        }
        aqs[e_loc][c] = aq;
        aks[e_loc][c] = ak;
        __syncthreads();
        const int c_ = tid >> 3, cq = tid & 7;
        float m0 = 0.f, m1 = 0.f, m2 = 0.f, m3 = 0.f;
        #pragma unroll
        for (int e = 0; e < 8; ++e) {
            const float a = aqs[e][c_];
            const float4 k4 = *(const float4*)&aks[e][cq * 4];
            m0 += a * k4.x; m1 += a * k4.y; m2 += a * k4.z; m3 += a * k4.w;
        }
        *(float4*)(Mpart + (long)blockIdx.x * 1024 + c_ * 32 + cq * 4) =
            make_float4(m0, m1, m2, m3);
    } else {
        __shared__ float us[512];
        float u0 = 0.f, u1 = 0.f;
        for (int n = 0; n < 512; ++n) {
            const float lw = lin_w[n];
            u0 += lw * wo[(long)n * 512 + tid];
            u1 += lw * wo[(long)n * 512 + tid + 256];
        }
        us[tid] = u0; us[tid + 256] = u1;
        ug[tid] = u0; ug[tid + 256] = u1;
        __syncthreads();
        float s0 = 0.f, s1 = 0.f;
        for (int d = 0; d < 512; ++d) {
            const float ud = us[d];
            s0 += ud * wv[(long)d * 512 + tid];
            s1 += ud * wv[(long)d * 512 + tid + 256];
        }
        v2g[tid] = s0; v2g[tid + 256] = s1;
    }
}

// ---- K2 (512 blocks): per (batch, 128x128 tile): in-block M-reduce
//      (ascending p, deterministic), build X/U tiles in LDS (linear write,
//      inverse-involution mapping), one K=32 3-term MFMA, wrapped-diag
//      reduce in LDS, then coalesced global atomicAdd into mc[b][512].
__global__ __launch_bounds__(256, 2) void corr_kernel(
    const float* __restrict__ x, const float* __restrict__ Mpart,
    float* __restrict__ mc)
{
    __shared__ ushort buf[16384];   // 4 regions x (128 rows x 4 units x 8 ush)
    __shared__ float Ml[32][36];
    __shared__ float mcloc[LL];
    ushort* bufAh = buf;
    ushort* bufAl = buf + 4096;
    ushort* bufBh = buf + 8192;
    ushort* bufBl = buf + 12288;
    const int tid = threadIdx.x;

    const int xcd = blockIdx.x & 7, s = blockIdx.x >> 3;
    const int b = xcd * 4 + (s >> 4);
    const int tile = s & 15;
    const int tm = tile >> 2, tn = tile & 3;

    // M reduce (ascending p -> deterministic, same bits every block)
    {
        float4 ms = make_float4(0.f, 0.f, 0.f, 0.f);
        for (int p = 0; p < 64; ++p) {
            const float4 v = *(const float4*)(Mpart + (long)p * 1024 + tid * 4);
            ms.x += v.x; ms.y += v.y; ms.z += v.z; ms.w += v.w;
        }
        *(float4*)&Ml[tid >> 3][(tid & 7) * 4] = ms;
    }
    mcloc[tid] = 0.f; mcloc[tid + 256] = 0.f;

    // per-thread build: 2 physical 16B units of one row per region
    const int r = tid >> 1;               // 0..127
    const int pb = (tid & 1) * 2;         // phys slots {0,1} or {2,3}
    const int swz = (r >> 1) & 3;
    const float* xA = x + ((long)b * LL + tm * 128 + r) * 32;
    const float* xB = x + ((long)b * LL + tn * 128 + r) * 32;
    float xb[32];
    #pragma unroll
    for (int q = 0; q < 8; ++q)
        *(float4*)&xb[q * 4] = *(const float4*)(xB + q * 4);

    __syncthreads();   // Ml + mcloc ready

    #pragma unroll
    for (int pi = 0; pi < 2; ++pi) {
        const int p = pb + pi;
        const int sl = p ^ swz;           // logical 8-col slot
        const int uoff = (r * 4 + p) * 8; // linear ushort offset in region
        const float4 a0 = *(const float4*)(xA + sl * 8);
        const float4 a1 = *(const float4*)(xA + sl * 8 + 4);
        const float xe[8] = {a0.x, a0.y, a0.z, a0.w, a1.x, a1.y, a1.z, a1.w};
        ushort xh[8], xl[8];
        #pragma unroll
        for (int j = 0; j < 8; ++j) split_bf(xe[j], xh[j], xl[j]);
        *(uint4*)(bufAh + uoff) = make_uint4(pk2(xh[0], xh[1]), pk2(xh[2], xh[3]),
                                             pk2(xh[4], xh[5]), pk2(xh[6], xh[7]));
        *(uint4*)(bufAl + uoff) = make_uint4(pk2(xl[0], xl[1]), pk2(xl[2], xl[3]),
                                             pk2(xl[4], xl[5]), pk2(xl[6], xl[7]));
        // U slot: u[c] = sum_d M[c][d] x[d] (q-ascending, bit-stable order)
        float uv[8];
        #pragma unroll
        for (int j = 0; j < 8; ++j) {
            const int c = sl * 8 + j;
            float sacc = 0.f;
            #pragma unroll
            for (int q = 0; q < 8; ++q) {
                const float4 m = *(const float4*)&Ml[c][q * 4];
                sacc += m.x * xb[q * 4] + m.y * xb[q * 4 + 1]
                      + m.z * xb[q * 4 + 2] + m.w * xb[q * 4 + 3];
            }
            uv[j] = sacc;
        }
        ushort uh[8], ul[8];
        #pragma unroll
        for (int j = 0; j < 8; ++j) split_bf(uv[j], uh[j], ul[j]);
        *(uint4*)(bufBh + uoff) = make_uint4(pk2(uh[0], uh[1]), pk2(uh[2], uh[3]),
                                             pk2(uh[4], uh[5]), pk2(uh[6], uh[7]));
        *(uint4*)(bufBl + uoff) = make_uint4(pk2(ul[0], ul[1]), pk2(ul[2], ul[3]),
                                             pk2(ul[4], ul[5]), pk2(ul[6], ul[7]));
    }
    __syncthreads();   // tiles built

    {
        const int wid = tid >> 6, lane = tid & 63;
        const int wr = (wid >> 1) * 64, wc = (wid & 1) * 64;
        const int fr = lane & 15, fs = lane >> 4;
        f32x4 acc[4][4] = {};
        mfma_step(bufAh, bufAl, bufBh, bufBl, acc, wr, wc, fr, fs);

        // pre-sum same-diagonal accs: diag = 16k + base, k = mi-ni
        const int base = wr - wc + 128 * (tm - tn) + fs * 4 - fr;
        #pragma unroll
        for (int k = -3; k <= 3; ++k) {
            #pragma unroll
            for (int rr = 0; rr < 4; ++rr) {
                float sdg = 0.f;
                #pragma unroll
                for (int mi = 0; mi < 4; ++mi) {
                    const int ni = mi - k;
                    if (ni >= 0 && ni < 4) sdg += acc[mi][ni][rr];
                }
                atomicAdd(&mcloc[(base + 16 * k + rr) & (LL - 1)], sdg);
            }
        }
    }
    __syncthreads();
    // block partial -> global mc[b] (coalesced device-scope float atomics;
    // 16 blocks/batch, order nondeterministic at ~1e-7 -- selection margin 2.6e-4)
    atomicAdd(&mc[b * 512 + tid], mcloc[tid]);
    atomicAdd(&mc[b * 512 + tid + 256], mcloc[tid + 256]);
}

// ---- K3 (32 blocks): per batch: top-6 (wave-shuffle) + softmax +
//      local w3/w4/c2 from ug/v2g + y.
__global__ __launch_bounds__(256) void tail_kernel(
    const float* __restrict__ mc, const float* __restrict__ x,
    const float* __restrict__ ug, const float* __restrict__ v2g,
    const float* __restrict__ cw, const float* __restrict__ cb,
    const float* __restrict__ lin_w, const float* __restrict__ bv,
    const float* __restrict__ bo, const float* __restrict__ lin_b,
    float* __restrict__ out)
{
    const int b = blockIdx.x, tid = threadIdx.x;
    const int lane = tid & 63, wid = tid >> 6;
    __shared__ float v2s[512];
    __shared__ float us2[512];
    __shared__ float w3p[8][32];
    __shared__ float w4p[8][32];
    __shared__ float w3s[32];
    __shared__ float w4s[32];
    __shared__ float c2s;
    __shared__ float swv[4];
    __shared__ int   swi[4];
    __shared__ float selv[TOPK];
    __shared__ int   seli[TOPK];
    __shared__ float wts[TOPK];
    __shared__ float redc[4];

    v2s[tid] = v2g[tid]; v2s[tid + 256] = v2g[tid + 256];
    us2[tid] = ug[tid];  us2[tid + 256] = ug[tid + 256];
    __syncthreads();
    {
        const int c = tid & 31, g = tid >> 5;
        float w3 = 0.f, w4 = 0.f;
        for (int dl = 0; dl < 64; ++dl) {
            const int d = g * 64 + dl;
            const float cwv = cw[(long)d * 32 + c];
            w3 += v2s[d] * cwv;
            w4 += lin_w[d] * cwv;
        }
        w3p[g][c] = w3; w4p[g][c] = w4;
    }
    __syncthreads();
    if (tid < 32) {
        float a3 = 0.f, a4 = 0.f;
        #pragma unroll
        for (int g2 = 0; g2 < 8; ++g2) { a3 += w3p[g2][tid]; a4 += w4p[g2][tid]; }
        w3s[tid] = a3; w4s[tid] = a4;
    }
    {
        float p = cb[tid] * (v2s[tid] + lin_w[tid])
                + cb[tid + 256] * (v2s[tid + 256] + lin_w[tid + 256])
                + bv[tid] * us2[tid] + bv[tid + 256] * us2[tid + 256]
                + bo[tid] * lin_w[tid] + bo[tid + 256] * lin_w[tid + 256];
        #pragma unroll
        for (int o = 32; o; o >>= 1) p += __shfl_down(p, o);
        if ((tid & 63) == 0) redc[tid >> 6] = p;
    }
    __syncthreads();
    if (tid == 0) c2s = redc[0] + redc[1] + redc[2] + redc[3] + lin_b[0];

    // mc (already fully reduced by corr's global atomics)
    float v0 = mc[b * 512 + tid] * (1.0f / DD);
    float v1 = mc[b * 512 + tid + 256] * (1.0f / DD);

    // top-6 via wave shuffle (max value, min index on ties)
    int live0 = 1, live1 = 1;
    for (int r = 0; r < TOPK; ++r) {
        float bvv = -1e30f; int bi = -1;
        if (live0) { bvv = v0; bi = tid; }
        if (live1 && v1 > bvv) { bvv = v1; bi = tid + 256; }
        #pragma unroll
        for (int o = 32; o; o >>= 1) {
            const float ov = __shfl_down(bvv, o);
            const int oi = __shfl_down(bi, o);
            if (ov > bvv || (ov == bvv && oi < bi)) { bvv = ov; bi = oi; }
        }
        if (lane == 0) { swv[wid] = bvv; swi[wid] = bi; }
        __syncthreads();
        if (tid == 0) {
            float fv = swv[0]; int fi = swi[0];
            #pragma unroll
            for (int w2 = 1; w2 < 4; ++w2) {
                if (swv[w2] > fv || (swv[w2] == fv && swi[w2] < fi)) { fv = swv[w2]; fi = swi[w2]; }
            }
            selv[r] = fv; seli[r] = fi;
        }
        __syncthreads();
        const int w = seli[r];
        if (w == tid)       live0 = 0;
        if (w == tid + 256) live1 = 0;
    }
    if (tid == 0) {
        const float mx = selv[0];
        float e[TOPK], ssum = 0.f;
        #pragma unroll
        for (int k = 0; k < TOPK; ++k) { e[k] = expf(selv[k] - mx); ssum += e[k]; }
        #pragma unroll
        for (int k = 0; k < TOPK; ++k) wts[k] = e[k] / ssum;
    }
    __syncthreads();

    // y = <xlast, w4> + <xmix, w3> + c2
    if (tid < CINN) {
        float xm = 0.f;
        #pragma unroll
        for (int k = 0; k < TOPK; ++k) {
            const int r = (LL - 1 + seli[k]) & (LL - 1);
            xm += wts[k] * x[((long)b * LL + r) * CINN + tid];
        }
        const float xlv = x[((long)b * LL + (LL - 1)) * CINN + tid];
        float yv = xlv * w4s[tid] + xm * w3s[tid];
        #pragma unroll
        for (int o = 16; o; o >>= 1) yv += __shfl_down(yv, o);
        if (tid == 0) out[b] = yv + c2s;
    }
}

extern "C" void kernel_launch(void* const* d_in, const int* in_sizes, int n_in,
                              void* d_out, int out_size, void* d_ws, size_t ws_size,
                              hipStream_t stream) {
    const float* x      = (const float*)d_in[0];
    const float* conv_w = (const float*)d_in[1];
    const float* conv_b = (const float*)d_in[2];
    const float* wq     = (const float*)d_in[3];
    const float* wk     = (const float*)d_in[5];
    const float* wv     = (const float*)d_in[7];
    const float* bv     = (const float*)d_in[8];
    const float* wo     = (const float*)d_in[9];
    const float* bo     = (const float*)d_in[10];
    const float* lin_w  = (const float*)d_in[11];
    const float* lin_b  = (const float*)d_in[12];
    // bq, bk and all bias terms inside mean_corr are tau-constant -> dropped
    // (softmax/top-k shift-invariant).

    char* w = (char*)d_ws;
    float* Mpart = (float*)w;  w += (long)64 * 1024 * 4;   // 256 KB
    float* ug    = (float*)w;  w += 512 * 4;
    float* v2g   = (float*)w;  w += 512 * 4;
    float* mc    = (float*)w;  w += (long)BB * 512 * 4;    // 64 KB
    float* yout  = (float*)d_out;

    // Mpart (0..63, also zeroes mc) | u->v2 chain (block 64)
    prep_kernel<<<65, 256, 0, stream>>>(wq, wk, conv_w, lin_w, wo, wv,
                                        Mpart, ug, v2g, mc);
    // corr tiles: in-block M-reduce + X/U build + MFMA + diag -> global-atomic mc
    corr_kernel<<<512, 256, 0, stream>>>(x, Mpart, mc);
    // top-6 + softmax + w3/w4/c2 + y
    tail_kernel<<<BB, 256, 0, stream>>>(mc, x, ug, v2g,
                                        conv_w, conv_b, lin_w, bv, bo, lin_b, yout);
}

// Round 14
// 65.590 us; speedup vs baseline: 1.4968x; 1.0689x over previous
//
#include <hip/hip_runtime.h>
#include <hip/hip_bf16.h>

#define LL 512
#define BB 32
#define DD 512
#define CINN 32
#define TOPK 6
#define BL (BB * LL)  // 16384

typedef __attribute__((ext_vector_type(8))) short bf16x8;
typedef __attribute__((ext_vector_type(4))) float f32x4;

__device__ inline float bf2f(ushort u) {
    union { uint i; float f; } c; c.i = ((uint)u) << 16; return c.f;
}
__device__ inline ushort f2bf(float f) {  // round-to-nearest-even
    union { float f; uint i; } c; c.f = f;
    uint i = c.i;
    return (ushort)((i + 0x7FFFu + ((i >> 16) & 1u)) >> 16);
}
__device__ inline void split_bf(float v, ushort& hi, ushort& lo) {
    hi = f2bf(v);
    lo = f2bf(v - bf2f(hi));
}
__device__ inline uint pk2(ushort a, ushort b) { return (uint)a | ((uint)b << 16); }

__device__ inline bf16x8 frag_ld(const ushort* sm, int r, int s) {
    return *(const bf16x8*)(sm + r * 32 + ((s ^ ((r >> 1) & 3)) << 3));
}

// One K=32 step of split-bf16 3-term MFMA (lo*lo dropped, ~2^-18).
__device__ inline void mfma_step(const ushort* sAh, const ushort* sAl,
                                 const ushort* sBh, const ushort* sBl,
                                 f32x4 acc[4][4], int wr, int wc, int fr, int fs) {
    bf16x8 bh[4], blo[4];
    #pragma unroll
    for (int ni = 0; ni < 4; ++ni) {
        bh[ni]  = frag_ld(sBh, wc + ni * 16 + fr, fs);
        blo[ni] = frag_ld(sBl, wc + ni * 16 + fr, fs);
    }
    #pragma unroll
    for (int mi = 0; mi < 4; ++mi) {
        const bf16x8 ah = frag_ld(sAh, wr + mi * 16 + fr, fs);
        const bf16x8 al = frag_ld(sAl, wr + mi * 16 + fr, fs);
        #pragma unroll
        for (int ni = 0; ni < 4; ++ni) {
            acc[mi][ni] = __builtin_amdgcn_mfma_f32_16x16x32_bf16(ah, bh[ni],  acc[mi][ni], 0, 0, 0);
            acc[mi][ni] = __builtin_amdgcn_mfma_f32_16x16x32_bf16(ah, blo[ni], acc[mi][ni], 0, 0, 0);
            acc[mi][ni] = __builtin_amdgcn_mfma_f32_16x16x32_bf16(al, bh[ni],  acc[mi][ni], 0, 0, 0);
        }
    }
}

// ---- K1 (73 blocks):
//  blocks 0..63: e-chunk i (8 rows): Mpart[i] = (wq_c@cw)^T (wk_c@cw) and
//                Wvc rows: Wvc[e][c] = sum_d wv[e][d] cw[d][c] (same loop).
//                Blocks 0..31 also zero mc[b].
//  blocks 64..71: upart[j] (64-n chunks of wo^T lin_w) and wvcb chunk
//                 (wvcb[e] = sum_d wv[e][d] cb[d], 4 threads/row).
//  block 72:      w4g[c] = sum_d lin_w[d] cw[d][c].
__global__ __launch_bounds__(256) void prep_kernel(
    const float* __restrict__ wq, const float* __restrict__ wk,
    const float* __restrict__ wv, const float* __restrict__ cw,
    const float* __restrict__ cb,
    const float* __restrict__ lin_w, const float* __restrict__ wo,
    float* __restrict__ Mpart, float* __restrict__ upart,
    float* __restrict__ Wvc, float* __restrict__ wvcb,
    float* __restrict__ w4g, float* __restrict__ mc)
{
    const int tid = threadIdx.x;
    if (blockIdx.x < 64) {
        __shared__ float cws[512][32];     // read: same d, c=bank -> conflict-free
        __shared__ float wqsT[512][9];     // stride 9: staging & reads conflict-free
        __shared__ float wksT[512][9];
        __shared__ float wvsT[512][9];
        __shared__ float aqs[8][32];
        __shared__ float aks[8][32];
        if (blockIdx.x < 32) {             // zero mc for this batch (every launch)
            mc[blockIdx.x * 512 + tid] = 0.f;
            mc[blockIdx.x * 512 + tid + 256] = 0.f;
        }
        for (int i = tid; i < 4096; i += 256) {
            const int d = i >> 3, q = i & 7;
            *(float4*)&cws[d][q * 4] = *(const float4*)(cw + (long)d * 32 + q * 4);
        }
        const int e0 = blockIdx.x * 8;
        for (int i = tid; i < 4096; i += 256) {
            const int e = i >> 9, d = i & 511;
            wqsT[d][e] = wq[(long)(e0 + e) * 512 + d];
            wksT[d][e] = wk[(long)(e0 + e) * 512 + d];
            wvsT[d][e] = wv[(long)(e0 + e) * 512 + d];
        }
        __syncthreads();
        const int e_loc = tid >> 5, c = tid & 31;
        float aq = 0.f, ak = 0.f, av = 0.f;
        #pragma unroll 4
        for (int d = 0; d < 512; ++d) {
            const float cv = cws[d][c];
            aq += wqsT[d][e_loc] * cv;
            ak += wksT[d][e_loc] * cv;
            av += wvsT[d][e_loc] * cv;
        }
        aqs[e_loc][c] = aq;
        aks[e_loc][c] = ak;
        Wvc[(long)(e0 + e_loc) * 32 + c] = av;
        __syncthreads();
        const int c_ = tid >> 3, cq = tid & 7;
        float m0 = 0.f, m1 = 0.f, m2 = 0.f, m3 = 0.f;
        #pragma unroll
        for (int e = 0; e < 8; ++e) {
            const float a = aqs[e][c_];
            const float4 k4 = *(const float4*)&aks[e][cq * 4];
            m0 += a * k4.x; m1 += a * k4.y; m2 += a * k4.z; m3 += a * k4.w;
        }
        *(float4*)(Mpart + (long)blockIdx.x * 1024 + c_ * 32 + cq * 4) =
            make_float4(m0, m1, m2, m3);
    } else if (blockIdx.x < 72) {
        const int j = blockIdx.x - 64;
        // upart chunk (64 n-rows)
        const int n0 = j * 64;
        float u0 = 0.f, u1 = 0.f;
        for (int n = 0; n < 64; ++n) {
            const float lw = lin_w[n0 + n];
            u0 += lw * wo[(long)(n0 + n) * 512 + tid];
            u1 += lw * wo[(long)(n0 + n) * 512 + tid + 256];
        }
        upart[j * 512 + tid] = u0;
        upart[j * 512 + tid + 256] = u1;
        // wvcb chunk: e = j*64 + (tid>>2), quarter (tid&3) covers 128 d's
        const int e = j * 64 + (tid >> 2);
        const int q = tid & 3;
        float p = 0.f;
        const float* wvr = wv + (long)e * 512 + q * 128;
        for (int dl = 0; dl < 128; ++dl) p += wvr[dl] * cb[q * 128 + dl];
        p += __shfl_xor(p, 1);
        p += __shfl_xor(p, 2);
        if (q == 0) wvcb[e] = p;
    } else {
        // w4g[c] = sum_d lin_w[d] cw[d][c]
        __shared__ float w4p[8][32];
        const int g = tid >> 5, c = tid & 31;
        float p = 0.f;
        for (int dl = 0; dl < 64; ++dl) {
            const int d = g * 64 + dl;
            p += lin_w[d] * cw[(long)d * 32 + c];
        }
        w4p[g][c] = p;
        __syncthreads();
        if (tid < 32) {
            float s = 0.f;
            #pragma unroll
            for (int g2 = 0; g2 < 8; ++g2) s += w4p[g2][tid];
            w4g[tid] = s;
        }
    }
}

// ---- K2 (512 blocks): per (batch, 128x128 tile): in-block M-reduce
//      (ascending p, deterministic), build X/U tiles in LDS (linear write,
//      inverse-involution mapping), one K=32 3-term MFMA, wrapped-diag
//      reduce in LDS, then coalesced global atomicAdd into mc[b][512].
__global__ __launch_bounds__(256, 2) void corr_kernel(
    const float* __restrict__ x, const float* __restrict__ Mpart,
    float* __restrict__ mc)
{
    __shared__ ushort buf[16384];   // 4 regions x (128 rows x 4 units x 8 ush)
    __shared__ float Ml[32][36];
    __shared__ float mcloc[LL];
    ushort* bufAh = buf;
    ushort* bufAl = buf + 4096;
    ushort* bufBh = buf + 8192;
    ushort* bufBl = buf + 12288;
    const int tid = threadIdx.x;

    const int xcd = blockIdx.x & 7, s = blockIdx.x >> 3;
    const int b = xcd * 4 + (s >> 4);
    const int tile = s & 15;
    const int tm = tile >> 2, tn = tile & 3;

    // M reduce (ascending p -> deterministic, same bits every block)
    {
        float4 ms = make_float4(0.f, 0.f, 0.f, 0.f);
        for (int p = 0; p < 64; ++p) {
            const float4 v = *(const float4*)(Mpart + (long)p * 1024 + tid * 4);
            ms.x += v.x; ms.y += v.y; ms.z += v.z; ms.w += v.w;
        }
        *(float4*)&Ml[tid >> 3][(tid & 7) * 4] = ms;
    }
    mcloc[tid] = 0.f; mcloc[tid + 256] = 0.f;

    // per-thread build: 2 physical 16B units of one row per region
    const int r = tid >> 1;               // 0..127
    const int pb = (tid & 1) * 2;         // phys slots {0,1} or {2,3}
    const int swz = (r >> 1) & 3;
    const float* xA = x + ((long)b * LL + tm * 128 + r) * 32;
    const float* xB = x + ((long)b * LL + tn * 128 + r) * 32;
    float xb[32];
    #pragma unroll
    for (int q = 0; q < 8; ++q)
        *(float4*)&xb[q * 4] = *(const float4*)(xB + q * 4);

    __syncthreads();   // Ml + mcloc ready

    #pragma unroll
    for (int pi = 0; pi < 2; ++pi) {
        const int p = pb + pi;
        const int sl = p ^ swz;           // logical 8-col slot
        const int uoff = (r * 4 + p) * 8; // linear ushort offset in region
        const float4 a0 = *(const float4*)(xA + sl * 8);
        const float4 a1 = *(const float4*)(xA + sl * 8 + 4);
        const float xe[8] = {a0.x, a0.y, a0.z, a0.w, a1.x, a1.y, a1.z, a1.w};
        ushort xh[8], xl[8];
        #pragma unroll
        for (int j = 0; j < 8; ++j) split_bf(xe[j], xh[j], xl[j]);
        *(uint4*)(bufAh + uoff) = make_uint4(pk2(xh[0], xh[1]), pk2(xh[2], xh[3]),
                                             pk2(xh[4], xh[5]), pk2(xh[6], xh[7]));
        *(uint4*)(bufAl + uoff) = make_uint4(pk2(xl[0], xl[1]), pk2(xl[2], xl[3]),
                                             pk2(xl[4], xl[5]), pk2(xl[6], xl[7]));
        // U slot: u[c] = sum_d M[c][d] x[d] (q-ascending, bit-stable order)
        float uv[8];
        #pragma unroll
        for (int j = 0; j < 8; ++j) {
            const int c = sl * 8 + j;
            float sacc = 0.f;
            #pragma unroll
            for (int q = 0; q < 8; ++q) {
                const float4 m = *(const float4*)&Ml[c][q * 4];
                sacc += m.x * xb[q * 4] + m.y * xb[q * 4 + 1]
                      + m.z * xb[q * 4 + 2] + m.w * xb[q * 4 + 3];
            }
            uv[j] = sacc;
        }
        ushort uh[8], ul[8];
        #pragma unroll
        for (int j = 0; j < 8; ++j) split_bf(uv[j], uh[j], ul[j]);
        *(uint4*)(bufBh + uoff) = make_uint4(pk2(uh[0], uh[1]), pk2(uh[2], uh[3]),
                                             pk2(uh[4], uh[5]), pk2(uh[6], uh[7]));
        *(uint4*)(bufBl + uoff) = make_uint4(pk2(ul[0], ul[1]), pk2(ul[2], ul[3]),
                                             pk2(ul[4], ul[5]), pk2(ul[6], ul[7]));
    }
    __syncthreads();   // tiles built

    {
        const int wid = tid >> 6, lane = tid & 63;
        const int wr = (wid >> 1) * 64, wc = (wid & 1) * 64;
        const int fr = lane & 15, fs = lane >> 4;
        f32x4 acc[4][4] = {};
        mfma_step(bufAh, bufAl, bufBh, bufBl, acc, wr, wc, fr, fs);

        // pre-sum same-diagonal accs: diag = 16k + base, k = mi-ni
        const int base = wr - wc + 128 * (tm - tn) + fs * 4 - fr;
        #pragma unroll
        for (int k = -3; k <= 3; ++k) {
            #pragma unroll
            for (int rr = 0; rr < 4; ++rr) {
                float sdg = 0.f;
                #pragma unroll
                for (int mi = 0; mi < 4; ++mi) {
                    const int ni = mi - k;
                    if (ni >= 0 && ni < 4) sdg += acc[mi][ni][rr];
                }
                atomicAdd(&mcloc[(base + 16 * k + rr) & (LL - 1)], sdg);
            }
        }
    }
    __syncthreads();
    // block partial -> global mc[b] (coalesced device-scope float atomics;
    // 16 blocks/batch, order nondeterministic at ~1e-7 -- selection margin 2.6e-4)
    atomicAdd(&mc[b * 512 + tid], mcloc[tid]);
    atomicAdd(&mc[b * 512 + tid + 256], mcloc[tid + 256]);
}

// ---- K3 (32 blocks): per batch: top-6 + softmax + w3 (from u, Wvc) +
//      w4 (precomputed) + c2 + y. All loops <= 64.
__global__ __launch_bounds__(256) void tail_kernel(
    const float* __restrict__ mc, const float* __restrict__ x,
    const float* __restrict__ upart, const float* __restrict__ Wvc,
    const float* __restrict__ wvcb, const float* __restrict__ w4g,
    const float* __restrict__ cb, const float* __restrict__ lin_w,
    const float* __restrict__ bv, const float* __restrict__ bo,
    const float* __restrict__ lin_b,
    float* __restrict__ out)
{
    const int b = blockIdx.x, tid = threadIdx.x;
    const int lane = tid & 63, wid = tid >> 6;
    __shared__ float us2[512];
    __shared__ float w3p[8][32];
    __shared__ float w3s[32];
    __shared__ float w4s[32];
    __shared__ float c2s;
    __shared__ float swv[4];
    __shared__ int   swi[4];
    __shared__ float selv[TOPK];
    __shared__ int   seli[TOPK];
    __shared__ float wts[TOPK];
    __shared__ float redc[4];

    // u = sum upart (ascending i, deterministic)
    {
        float b0 = 0.f, b1 = 0.f;
        #pragma unroll
        for (int i = 0; i < 8; ++i) {
            b0 += upart[i * 512 + tid];
            b1 += upart[i * 512 + tid + 256];
        }
        us2[tid] = b0; us2[tid + 256] = b1;
    }
    __syncthreads();
    // w3[c] = sum_e u[e] Wvc[e][c]  (8 e-groups x 32 c)
    {
        const int g = tid >> 5, c = tid & 31;
        float p = 0.f;
        for (int el = 0; el < 64; ++el) {
            const int e = g * 64 + el;
            p += us2[e] * Wvc[(long)e * 32 + c];
        }
        w3p[g][c] = p;
    }
    __syncthreads();
    if (tid < 32) {
        float s = 0.f;
        #pragma unroll
        for (int g2 = 0; g2 < 8; ++g2) s += w3p[g2][tid];
        w3s[tid] = s;
        w4s[tid] = w4g[tid];
    }
    // c2 = <u, wvcb> + <cb,lin_w> + <bv,u> + <bo,lin_w> + lin_b
    {
        float p = us2[tid] * (wvcb[tid] + bv[tid])
                + us2[tid + 256] * (wvcb[tid + 256] + bv[tid + 256])
                + lin_w[tid] * (cb[tid] + bo[tid])
                + lin_w[tid + 256] * (cb[tid + 256] + bo[tid + 256]);
        #pragma unroll
        for (int o = 32; o; o >>= 1) p += __shfl_down(p, o);
        if ((tid & 63) == 0) redc[tid >> 6] = p;
    }
    __syncthreads();
    if (tid == 0) c2s = redc[0] + redc[1] + redc[2] + redc[3] + lin_b[0];

    // mc (already fully reduced by corr's global atomics)
    float v0 = mc[b * 512 + tid] * (1.0f / DD);
    float v1 = mc[b * 512 + tid + 256] * (1.0f / DD);

    // top-6 via wave shuffle (max value, min index on ties)
    int live0 = 1, live1 = 1;
    for (int r = 0; r < TOPK; ++r) {
        float bvv = -1e30f; int bi = -1;
        if (live0) { bvv = v0; bi = tid; }
        if (live1 && v1 > bvv) { bvv = v1; bi = tid + 256; }
        #pragma unroll
        for (int o = 32; o; o >>= 1) {
            const float ov = __shfl_down(bvv, o);
            const int oi = __shfl_down(bi, o);
            if (ov > bvv || (ov == bvv && oi < bi)) { bvv = ov; bi = oi; }
        }
        if (lane == 0) { swv[wid] = bvv; swi[wid] = bi; }
        __syncthreads();
        if (tid == 0) {
            float fv = swv[0]; int fi = swi[0];
            #pragma unroll
            for (int w2 = 1; w2 < 4; ++w2) {
                if (swv[w2] > fv || (swv[w2] == fv && swi[w2] < fi)) { fv = swv[w2]; fi = swi[w2]; }
            }
            selv[r] = fv; seli[r] = fi;
        }
        __syncthreads();
        const int w = seli[r];
        if (w == tid)       live0 = 0;
        if (w == tid + 256) live1 = 0;
    }
    if (tid == 0) {
        const float mx = selv[0];
        float e[TOPK], ssum = 0.f;
        #pragma unroll
        for (int k = 0; k < TOPK; ++k) { e[k] = expf(selv[k] - mx); ssum += e[k]; }
        #pragma unroll
        for (int k = 0; k < TOPK; ++k) wts[k] = e[k] / ssum;
    }
    __syncthreads();

    // y = <xlast, w4> + <xmix, w3> + c2
    if (tid < CINN) {
        float xm = 0.f;
        #pragma unroll
        for (int k = 0; k < TOPK; ++k) {
            const int r = (LL - 1 + seli[k]) & (LL - 1);
            xm += wts[k] * x[((long)b * LL + r) * CINN + tid];
        }
        const float xlv = x[((long)b * LL + (LL - 1)) * CINN + tid];
        float yv = xlv * w4s[tid] + xm * w3s[tid];
        #pragma unroll
        for (int o = 16; o; o >>= 1) yv += __shfl_down(yv, o);
        if (tid == 0) out[b] = yv + c2s;
    }
}

extern "C" void kernel_launch(void* const* d_in, const int* in_sizes, int n_in,
                              void* d_out, int out_size, void* d_ws, size_t ws_size,
                              hipStream_t stream) {
    const float* x      = (const float*)d_in[0];
    const float* conv_w = (const float*)d_in[1];
    const float* conv_b = (const float*)d_in[2];
    const float* wq     = (const float*)d_in[3];
    const float* wk     = (const float*)d_in[5];
    const float* wv     = (const float*)d_in[7];
    const float* bv     = (const float*)d_in[8];
    const float* wo     = (const float*)d_in[9];
    const float* bo     = (const float*)d_in[10];
    const float* lin_w  = (const float*)d_in[11];
    const float* lin_b  = (const float*)d_in[12];
    // bq, bk and all bias terms inside mean_corr are tau-constant -> dropped
    // (softmax/top-k shift-invariant).

    char* w = (char*)d_ws;
    float* Mpart = (float*)w;  w += (long)64 * 1024 * 4;   // 256 KB
    float* upart = (float*)w;  w += (long)8 * 512 * 4;     // 16 KB
    float* Wvc   = (float*)w;  w += (long)512 * 32 * 4;    // 64 KB
    float* wvcb  = (float*)w;  w += 512 * 4;
    float* w4g   = (float*)w;  w += 32 * 4;
    float* mc    = (float*)w;  w += (long)BB * 512 * 4;    // 64 KB
    float* yout  = (float*)d_out;

    // Mpart + Wvc (0..63, also zeroes mc) | upart + wvcb (64..71) | w4 (72)
    prep_kernel<<<73, 256, 0, stream>>>(wq, wk, wv, conv_w, conv_b, lin_w, wo,
                                        Mpart, upart, Wvc, wvcb, w4g, mc);
    // corr tiles: in-block M-reduce + X/U build + MFMA + diag -> global-atomic mc
    corr_kernel<<<512, 256, 0, stream>>>(x, Mpart, mc);
    // top-6 + softmax + w3/w4/c2 + y
    tail_kernel<<<BB, 256, 0, stream>>>(mc, x, upart, Wvc, wvcb, w4g,
                                        conv_b, lin_w, bv, bo, lin_b, yout);
}

// Round 15
// 59.898 us; speedup vs baseline: 1.6390x; 1.0950x over previous
//
#include <hip/hip_runtime.h>
#include <hip/hip_bf16.h>

#define LL 512
#define BB 32
#define DD 512
#define CINN 32
#define TOPK 6
#define BL (BB * LL)  // 16384

typedef __attribute__((ext_vector_type(8))) short bf16x8;
typedef __attribute__((ext_vector_type(4))) float f32x4;

__device__ inline float bf2f(ushort u) {
    union { uint i; float f; } c; c.i = ((uint)u) << 16; return c.f;
}
__device__ inline ushort f2bf(float f) {  // round-to-nearest-even
    union { float f; uint i; } c; c.f = f;
    uint i = c.i;
    return (ushort)((i + 0x7FFFu + ((i >> 16) & 1u)) >> 16);
}
__device__ inline void split_bf(float v, ushort& hi, ushort& lo) {
    hi = f2bf(v);
    lo = f2bf(v - bf2f(hi));
}
__device__ inline uint pk2(ushort a, ushort b) { return (uint)a | ((uint)b << 16); }

__device__ inline bf16x8 frag_ld(const ushort* sm, int r, int s) {
    return *(const bf16x8*)(sm + r * 32 + ((s ^ ((r >> 1) & 3)) << 3));
}

// One K=32 step of split-bf16 3-term MFMA (lo*lo dropped, ~2^-18).
__device__ inline void mfma_step(const ushort* sAh, const ushort* sAl,
                                 const ushort* sBh, const ushort* sBl,
                                 f32x4 acc[4][4], int wr, int wc, int fr, int fs) {
    bf16x8 bh[4], blo[4];
    #pragma unroll
    for (int ni = 0; ni < 4; ++ni) {
        bh[ni]  = frag_ld(sBh, wc + ni * 16 + fr, fs);
        blo[ni] = frag_ld(sBl, wc + ni * 16 + fr, fs);
    }
    #pragma unroll
    for (int mi = 0; mi < 4; ++mi) {
        const bf16x8 ah = frag_ld(sAh, wr + mi * 16 + fr, fs);
        const bf16x8 al = frag_ld(sAl, wr + mi * 16 + fr, fs);
        #pragma unroll
        for (int ni = 0; ni < 4; ++ni) {
            acc[mi][ni] = __builtin_amdgcn_mfma_f32_16x16x32_bf16(ah, bh[ni],  acc[mi][ni], 0, 0, 0);
            acc[mi][ni] = __builtin_amdgcn_mfma_f32_16x16x32_bf16(ah, blo[ni], acc[mi][ni], 0, 0, 0);
            acc[mi][ni] = __builtin_amdgcn_mfma_f32_16x16x32_bf16(al, bh[ni],  acc[mi][ni], 0, 0, 0);
        }
    }
}

// ---- K1 (72 blocks):
//  blocks 0..63:  e-chunk i (8 rows of wq,wk): Mpart[i] = (wq_c@cw)^T (wk_c@cw).
//                 Blocks 0..31 also zero mc[b] (re-zeroed every launch).
//  blocks 64..71: upart[j][d] = sum_{n in 64-chunk} lin_w[n] wo[n][d].
__global__ __launch_bounds__(256) void prep_m(
    const float* __restrict__ wq, const float* __restrict__ wk,
    const float* __restrict__ cw,
    const float* __restrict__ lin_w, const float* __restrict__ wo,
    float* __restrict__ Mpart, float* __restrict__ upart,
    float* __restrict__ mc)
{
    const int tid = threadIdx.x;
    if (blockIdx.x < 64) {
        __shared__ float cws[512][32];     // read: same d, c=bank -> conflict-free
        __shared__ float wqsT[512][9];     // stride 9: staging & reads conflict-free
        __shared__ float wksT[512][9];
        __shared__ float aqs[8][32];
        __shared__ float aks[8][32];
        if (blockIdx.x < 32) {             // zero mc for this batch (every launch)
            mc[blockIdx.x * 512 + tid] = 0.f;
            mc[blockIdx.x * 512 + tid + 256] = 0.f;
        }
        for (int i = tid; i < 4096; i += 256) {
            const int d = i >> 3, q = i & 7;
            *(float4*)&cws[d][q * 4] = *(const float4*)(cw + (long)d * 32 + q * 4);
        }
        const int e0 = blockIdx.x * 8;
        for (int i = tid; i < 4096; i += 256) {
            const int e = i >> 9, d = i & 511;
            wqsT[d][e] = wq[(long)(e0 + e) * 512 + d];
            wksT[d][e] = wk[(long)(e0 + e) * 512 + d];
        }
        __syncthreads();
        const int e_loc = tid >> 5, c = tid & 31;
        float aq = 0.f, ak = 0.f;
        #pragma unroll 4
        for (int d = 0; d < 512; ++d) {
            const float cv = cws[d][c];
            aq += wqsT[d][e_loc] * cv;
            ak += wksT[d][e_loc] * cv;
        }
        aqs[e_loc][c] = aq;
        aks[e_loc][c] = ak;
        __syncthreads();
        const int c_ = tid >> 3, cq = tid & 7;
        float m0 = 0.f, m1 = 0.f, m2 = 0.f, m3 = 0.f;
        #pragma unroll
        for (int e = 0; e < 8; ++e) {
            const float a = aqs[e][c_];
            const float4 k4 = *(const float4*)&aks[e][cq * 4];
            m0 += a * k4.x; m1 += a * k4.y; m2 += a * k4.z; m3 += a * k4.w;
        }
        *(float4*)(Mpart + (long)blockIdx.x * 1024 + c_ * 32 + cq * 4) =
            make_float4(m0, m1, m2, m3);
    } else {
        const int j = blockIdx.x - 64;
        const int n0 = j * 64;
        float u0 = 0.f, u1 = 0.f;
        for (int n = 0; n < 64; ++n) {
            const float lw = lin_w[n0 + n];
            u0 += lw * wo[(long)(n0 + n) * 512 + tid];
            u1 += lw * wo[(long)(n0 + n) * 512 + tid + 256];
        }
        upart[j * 512 + tid] = u0;
        upart[j * 512 + tid + 256] = u1;
    }
}

// ---- K2 (12 blocks): 0..3: Mfin = sum_p Mpart (ascending p, deterministic).
//                      4..11: v2part[j][e] = sum_{d in 64-chunk} u[d] wv[d][e].
__global__ __launch_bounds__(256) void prep_s(
    const float* __restrict__ Mpart, const float* __restrict__ upart,
    const float* __restrict__ wv,
    float* __restrict__ Mfin, float* __restrict__ v2part)
{
    const int tid = threadIdx.x;
    if (blockIdx.x < 4) {
        const int entry = blockIdx.x * 256 + tid;
        float s = 0.f;
        for (int p = 0; p < 64; ++p) s += Mpart[(long)p * 1024 + entry];
        Mfin[entry] = s;
    } else {
        const int j = blockIdx.x - 4;
        __shared__ float us[64];
        if (tid < 64) {
            float s = 0.f;
            #pragma unroll
            for (int i = 0; i < 8; ++i) s += upart[i * 512 + j * 64 + tid];
            us[tid] = s;
        }
        __syncthreads();
        float s0 = 0.f, s1 = 0.f;
        for (int dl = 0; dl < 64; ++dl) {
            const float ud = us[dl];
            s0 += ud * wv[(long)(j * 64 + dl) * 512 + tid];
            s1 += ud * wv[(long)(j * 64 + dl) * 512 + tid + 256];
        }
        v2part[j * 512 + tid] = s0;
        v2part[j * 512 + tid + 256] = s1;
    }
}

// ---- K3 (512 blocks): per (batch, 128x128 tile): load M (4KB Mfin), build
//      X-split and U = M x tiles in LDS (linear ds_write, inverse-involution
//      mapping), one K=32 3-term MFMA, wrapped-diag reduce in LDS, then
//      coalesced global atomicAdd into mc[b][512].
__global__ __launch_bounds__(256, 2) void corr_kernel(
    const float* __restrict__ x, const float* __restrict__ Mfin,
    float* __restrict__ mc)
{
    __shared__ ushort buf[16384];   // 4 regions x (128 rows x 4 units x 8 ush)
    __shared__ float Ml[32][36];
    __shared__ float mcloc[LL];
    ushort* bufAh = buf;
    ushort* bufAl = buf + 4096;
    ushort* bufBh = buf + 8192;
    ushort* bufBl = buf + 12288;
    const int tid = threadIdx.x;

    const int xcd = blockIdx.x & 7, s = blockIdx.x >> 3;
    const int b = xcd * 4 + (s >> 4);
    const int tile = s & 15;
    const int tm = tile >> 2, tn = tile & 3;

    {
        const float4 mv = *(const float4*)(Mfin + tid * 4);
        *(float4*)&Ml[tid >> 3][(tid & 7) * 4] = mv;
    }
    mcloc[tid] = 0.f; mcloc[tid + 256] = 0.f;

    // per-thread build: 2 physical 16B units of one row per region
    const int r = tid >> 1;               // 0..127
    const int pb = (tid & 1) * 2;         // phys slots {0,1} or {2,3}
    const int swz = (r >> 1) & 3;
    const float* xA = x + ((long)b * LL + tm * 128 + r) * 32;
    const float* xB = x + ((long)b * LL + tn * 128 + r) * 32;
    float xb[32];
    #pragma unroll
    for (int q = 0; q < 8; ++q)
        *(float4*)&xb[q * 4] = *(const float4*)(xB + q * 4);

    __syncthreads();   // Ml + mcloc ready

    #pragma unroll
    for (int pi = 0; pi < 2; ++pi) {
        const int p = pb + pi;
        const int sl = p ^ swz;           // logical 8-col slot
        const int uoff = (r * 4 + p) * 8; // linear ushort offset in region
        const float4 a0 = *(const float4*)(xA + sl * 8);
        const float4 a1 = *(const float4*)(xA + sl * 8 + 4);
        const float xe[8] = {a0.x, a0.y, a0.z, a0.w, a1.x, a1.y, a1.z, a1.w};
        ushort xh[8], xl[8];
        #pragma unroll
        for (int j = 0; j < 8; ++j) split_bf(xe[j], xh[j], xl[j]);
        *(uint4*)(bufAh + uoff) = make_uint4(pk2(xh[0], xh[1]), pk2(xh[2], xh[3]),
                                             pk2(xh[4], xh[5]), pk2(xh[6], xh[7]));
        *(uint4*)(bufAl + uoff) = make_uint4(pk2(xl[0], xl[1]), pk2(xl[2], xl[3]),
                                             pk2(xl[4], xl[5]), pk2(xl[6], xl[7]));
        // U slot: u[c] = sum_d M[c][d] x[d] (q-ascending, bit-stable order)
        float uv[8];
        #pragma unroll
        for (int j = 0; j < 8; ++j) {
            const int c = sl * 8 + j;
            float sacc = 0.f;
            #pragma unroll
            for (int q = 0; q < 8; ++q) {
                const float4 m = *(const float4*)&Ml[c][q * 4];
                sacc += m.x * xb[q * 4] + m.y * xb[q * 4 + 1]
                      + m.z * xb[q * 4 + 2] + m.w * xb[q * 4 + 3];
            }
            uv[j] = sacc;
        }
        ushort uh[8], ul[8];
        #pragma unroll
        for (int j = 0; j < 8; ++j) split_bf(uv[j], uh[j], ul[j]);
        *(uint4*)(bufBh + uoff) = make_uint4(pk2(uh[0], uh[1]), pk2(uh[2], uh[3]),
                                             pk2(uh[4], uh[5]), pk2(uh[6], uh[7]));
        *(uint4*)(bufBl + uoff) = make_uint4(pk2(ul[0], ul[1]), pk2(ul[2], ul[3]),
                                             pk2(ul[4], ul[5]), pk2(ul[6], ul[7]));
    }
    __syncthreads();   // tiles built

    {
        const int wid = tid >> 6, lane = tid & 63;
        const int wr = (wid >> 1) * 64, wc = (wid & 1) * 64;
        const int fr = lane & 15, fs = lane >> 4;
        f32x4 acc[4][4] = {};
        mfma_step(bufAh, bufAl, bufBh, bufBl, acc, wr, wc, fr, fs);

        // pre-sum same-diagonal accs: diag = 16k + base, k = mi-ni
        const int base = wr - wc + 128 * (tm - tn) + fs * 4 - fr;
        #pragma unroll
        for (int k = -3; k <= 3; ++k) {
            #pragma unroll
            for (int rr = 0; rr < 4; ++rr) {
                float sdg = 0.f;
                #pragma unroll
                for (int mi = 0; mi < 4; ++mi) {
                    const int ni = mi - k;
                    if (ni >= 0 && ni < 4) sdg += acc[mi][ni][rr];
                }
                atomicAdd(&mcloc[(base + 16 * k + rr) & (LL - 1)], sdg);
            }
        }
    }
    __syncthreads();
    // block partial -> global mc[b] (coalesced device-scope float atomics;
    // 16 blocks/batch, order nondeterministic at ~1e-7 -- selection margin 2.6e-4)
    atomicAdd(&mc[b * 512 + tid], mcloc[tid]);
    atomicAdd(&mc[b * 512 + tid + 256], mcloc[tid + 256]);
}

// ---- K4 (32 blocks): per batch: top-6 (wave-shuffle) + softmax +
//      local w3/w4/c2 from upart/v2part + y.
__global__ __launch_bounds__(256) void tail_kernel(
    const float* __restrict__ mc, const float* __restrict__ x,
    const float* __restrict__ upart, const float* __restrict__ v2part,
    const float* __restrict__ cw, const float* __restrict__ cb,
    const float* __restrict__ lin_w, const float* __restrict__ bv,
    const float* __restrict__ bo, const float* __restrict__ lin_b,
    float* __restrict__ out)
{
    const int b = blockIdx.x, tid = threadIdx.x;
    const int lane = tid & 63, wid = tid >> 6;
    __shared__ float v2s[512];
    __shared__ float us2[512];
    __shared__ float w3p[8][32];
    __shared__ float w4p[8][32];
    __shared__ float w3s[32];
    __shared__ float w4s[32];
    __shared__ float c2s;
    __shared__ float swv[4];
    __shared__ int   swi[4];
    __shared__ float selv[TOPK];
    __shared__ int   seli[TOPK];
    __shared__ float wts[TOPK];
    __shared__ float redc[4];

    {
        float a0 = 0.f, a1 = 0.f, b0 = 0.f, b1 = 0.f;
        #pragma unroll
        for (int i = 0; i < 8; ++i) {
            a0 += v2part[i * 512 + tid];
            a1 += v2part[i * 512 + tid + 256];
            b0 += upart[i * 512 + tid];
            b1 += upart[i * 512 + tid + 256];
        }
        v2s[tid] = a0; v2s[tid + 256] = a1;
        us2[tid] = b0; us2[tid + 256] = b1;
    }
    __syncthreads();
    {
        const int c = tid & 31, g = tid >> 5;
        float w3 = 0.f, w4 = 0.f;
        for (int dl = 0; dl < 64; ++dl) {
            const int d = g * 64 + dl;
            const float cwv = cw[(long)d * 32 + c];
            w3 += v2s[d] * cwv;
            w4 += lin_w[d] * cwv;
        }
        w3p[g][c] = w3; w4p[g][c] = w4;
    }
    __syncthreads();
    if (tid < 32) {
        float a3 = 0.f, a4 = 0.f;
        #pragma unroll
        for (int g2 = 0; g2 < 8; ++g2) { a3 += w3p[g2][tid]; a4 += w4p[g2][tid]; }
        w3s[tid] = a3; w4s[tid] = a4;
    }
    {
        float p = cb[tid] * (v2s[tid] + lin_w[tid])
                + cb[tid + 256] * (v2s[tid + 256] + lin_w[tid + 256])
                + bv[tid] * us2[tid] + bv[tid + 256] * us2[tid + 256]
                + bo[tid] * lin_w[tid] + bo[tid + 256] * lin_w[tid + 256];
        #pragma unroll
        for (int o = 32; o; o >>= 1) p += __shfl_down(p, o);
        if ((tid & 63) == 0) redc[tid >> 6] = p;
    }
    __syncthreads();
    if (tid == 0) c2s = redc[0] + redc[1] + redc[2] + redc[3] + lin_b[0];

    // mc already fully reduced by corr's global atomics
    float v0 = mc[b * 512 + tid] * (1.0f / DD);
    float v1 = mc[b * 512 + tid + 256] * (1.0f / DD);

    // top-6 via wave shuffle (max value, min index on ties)
    int live0 = 1, live1 = 1;
    for (int r = 0; r < TOPK; ++r) {
        float bvv = -1e30f; int bi = -1;
        if (live0) { bvv = v0; bi = tid; }
        if (live1 && v1 > bvv) { bvv = v1; bi = tid + 256; }
        #pragma unroll
        for (int o = 32; o; o >>= 1) {
            const float ov = __shfl_down(bvv, o);
            const int oi = __shfl_down(bi, o);
            if (ov > bvv || (ov == bvv && oi < bi)) { bvv = ov; bi = oi; }
        }
        if (lane == 0) { swv[wid] = bvv; swi[wid] = bi; }
        __syncthreads();
        if (tid == 0) {
            float fv = swv[0]; int fi = swi[0];
            #pragma unroll
            for (int w2 = 1; w2 < 4; ++w2) {
                if (swv[w2] > fv || (swv[w2] == fv && swi[w2] < fi)) { fv = swv[w2]; fi = swi[w2]; }
            }
            selv[r] = fv; seli[r] = fi;
        }
        __syncthreads();
        const int w = seli[r];
        if (w == tid)       live0 = 0;
        if (w == tid + 256) live1 = 0;
    }
    if (tid == 0) {
        const float mx = selv[0];
        float e[TOPK], ssum = 0.f;
        #pragma unroll
        for (int k = 0; k < TOPK; ++k) { e[k] = expf(selv[k] - mx); ssum += e[k]; }
        #pragma unroll
        for (int k = 0; k < TOPK; ++k) wts[k] = e[k] / ssum;
    }
    __syncthreads();

    // y = <xlast, w4> + <xmix, w3> + c2
    if (tid < CINN) {
        float xm = 0.f;
        #pragma unroll
        for (int k = 0; k < TOPK; ++k) {
            const int r = (LL - 1 + seli[k]) & (LL - 1);
            xm += wts[k] * x[((long)b * LL + r) * CINN + tid];
        }
        const float xlv = x[((long)b * LL + (LL - 1)) * CINN + tid];
        float yv = xlv * w4s[tid] + xm * w3s[tid];
        #pragma unroll
        for (int o = 16; o; o >>= 1) yv += __shfl_down(yv, o);
        if (tid == 0) out[b] = yv + c2s;
    }
}

extern "C" void kernel_launch(void* const* d_in, const int* in_sizes, int n_in,
                              void* d_out, int out_size, void* d_ws, size_t ws_size,
                              hipStream_t stream) {
    const float* x      = (const float*)d_in[0];
    const float* conv_w = (const float*)d_in[1];
    const float* conv_b = (const float*)d_in[2];
    const float* wq     = (const float*)d_in[3];
    const float* wk     = (const float*)d_in[5];
    const float* wv     = (const float*)d_in[7];
    const float* bv     = (const float*)d_in[8];
    const float* wo     = (const float*)d_in[9];
    const float* bo     = (const float*)d_in[10];
    const float* lin_w  = (const float*)d_in[11];
    const float* lin_b  = (const float*)d_in[12];
    // bq, bk and all bias terms inside mean_corr are tau-constant -> dropped
    // (softmax/top-k shift-invariant).

    char* w = (char*)d_ws;
    float* Mpart  = (float*)w;  w += (long)64 * 1024 * 4;   // 256 KB
    float* upart  = (float*)w;  w += (long)8 * 512 * 4;     // 16 KB
    float* Mfin   = (float*)w;  w += (long)1024 * 4;        // 4 KB
    float* v2part = (float*)w;  w += (long)8 * 512 * 4;     // 16 KB
    float* mc     = (float*)w;  w += (long)BB * 512 * 4;    // 64 KB
    float* yout   = (float*)d_out;

    // Mpart (0..63, also zeroes mc) | upart (64..71)
    prep_m<<<72, 256, 0, stream>>>(wq, wk, conv_w, lin_w, wo, Mpart, upart, mc);
    // Mfin (0..3, ascending-p deterministic) | v2part (4..11)
    prep_s<<<12, 256, 0, stream>>>(Mpart, upart, wv, Mfin, v2part);
    // corr tiles: Mfin load (4KB) + X/U build + MFMA + diag -> global-atomic mc
    corr_kernel<<<512, 256, 0, stream>>>(x, Mfin, mc);
    // top-6 + softmax + w3/w4/c2 + y
    tail_kernel<<<BB, 256, 0, stream>>>(mc, x, upart, v2part,
                                        conv_w, conv_b, lin_w, bv, bo, lin_b, yout);
}